// Round 6
// baseline (328.478 us; speedup 1.0000x reference)
//
#include <hip/hip_runtime.h>
#include <hip/hip_bf16.h>
#include <math.h>

// ---- problem constants (structural, from the reference) ----
#define NB      2
#define QN      12240
#define HW_TOT  12240
#define DIMS    256
#define HEADS   8
#define CH      32
#define LEVELS  4
#define POINTS  4
#define M_TOT   (NB * QN)        // 24480

typedef unsigned short ushort_t;
typedef __attribute__((ext_vector_type(8))) short short8;
typedef __attribute__((ext_vector_type(4))) float floatx4;

__device__ __constant__ int c_Hl[4]    = {96, 48, 24, 12};
__device__ __constant__ int c_Wl[4]    = {96, 48, 24, 12};
__device__ __constant__ int c_start[4] = {0, 9216, 11520, 12096};

__device__ __forceinline__ ushort_t f2bf(float f) {
    __hip_bfloat16 h = __float2bfloat16(f);
    return *reinterpret_cast<ushort_t*>(&h);
}

// =====================================================================
// Elementwise fp32 -> bf16 for v and q (one pass, 8 elems/thread).
// =====================================================================
__global__ __launch_bounds__(256) void convert_qv_kernel(
    const float* __restrict__ v, const float* __restrict__ q,
    ushort_t* __restrict__ vbf, ushort_t* __restrict__ qbf)
{
    const size_t i = ((size_t)blockIdx.x * 256 + threadIdx.x) * 8;
    const size_t half = (size_t)M_TOT * DIMS;
    const float* src; ushort_t* dst; size_t off;
    if (i < half) { src = v; dst = vbf; off = i; }
    else          { src = q; dst = qbf; off = i - half; }
    const float4 a = *(const float4*)&src[off];
    const float4 b = *(const float4*)&src[off + 4];
    ushort_t t[8] = {f2bf(a.x), f2bf(a.y), f2bf(a.z), f2bf(a.w),
                     f2bf(b.x), f2bf(b.y), f2bf(b.z), f2bf(b.w)};
    *(int4*)&dst[off] = *(int4*)t;
}

// =====================================================================
// Weights -> transposed bf16 (WT[n][k]); z=1 also builds the fused
// off+attn weight [384][256] and its combined bias.
// =====================================================================
__global__ __launch_bounds__(256) void prep_weights_kernel(
    const float* __restrict__ W_in, const float* __restrict__ W_off,
    const float* __restrict__ W_attn, const float* __restrict__ W_out,
    const float* __restrict__ b_off, const float* __restrict__ b_attn,
    ushort_t* __restrict__ Tin, ushort_t* __restrict__ Tcomb,
    ushort_t* __restrict__ Tout, float* __restrict__ bcomb)
{
    const int z  = blockIdx.z;
    const int gi = blockIdx.x * 256 + threadIdx.x;
    if (z == 1 && gi < 384)
        bcomb[gi] = (gi < 256) ? b_off[gi] : b_attn[gi - 256];
    const int Nw = (z == 1) ? 384 : 256;
    if (gi >= Nw * 256) return;
    const int k = gi & 255;       // coalesced write along k
    const int n = gi >> 8;
    float val; ushort_t* T;
    if (z == 0)      { val = W_in[k * 256 + n];  T = Tin;  }
    else if (z == 1) { val = (n < 256) ? W_off[k * 256 + n]
                                       : W_attn[k * 128 + (n - 256)]; T = Tcomb; }
    else             { val = W_out[k * 256 + n]; T = Tout; }
    T[n * 256 + k] = f2bf(val);
}

// =====================================================================
// Direct-load bf16 MFMA GEMM (no LDS, no barriers): K=256 fixed.
// Each wave computes a 64x64 tile via 4x4 v_mfma_f32_16x16x32_bf16.
// A-operand fragment A[m=l16][k=quad*8+j] is a contiguous 16B chunk of
// row-major A -> global_load_dwordx4 straight into VGPRs; same for BT.
// No __syncthreads -> compiler pipelines loads across the whole K-loop
// with fine-grained vmcnt(N).  B (weights) and re-read A rows are L2-hot.
// M-tail: rows clamped to M-1 (those products land in C rows >= M,
// never stored).
// =====================================================================
template<bool C_BF16>
__device__ __forceinline__ void gemm_direct(
    const ushort_t* __restrict__ A, const ushort_t* __restrict__ BT,
    const float* __restrict__ bias, void* __restrict__ Cv,
    int M, int Nc, int bm0, int bn0)
{
    const int tid  = threadIdx.x;
    const int wave = tid >> 6;
    const int lane = tid & 63;
    const int quad = lane >> 4;
    const int l16  = lane & 15;
    const int wm   = (wave >> 1) * 64;
    const int wn   = (wave & 1) * 64;

    const ushort_t* ap[4];
    const ushort_t* bp[4];
    #pragma unroll
    for (int mt = 0; mt < 4; ++mt) {
        int r = bm0 + wm + mt * 16 + l16;
        if (r > M - 1) r = M - 1;
        ap[mt] = A + (size_t)r * 256 + quad * 8;
    }
    #pragma unroll
    for (int nt = 0; nt < 4; ++nt)
        bp[nt] = BT + (size_t)(bn0 + wn + nt * 16 + l16) * 256 + quad * 8;

    floatx4 acc[4][4];
    #pragma unroll
    for (int i = 0; i < 4; ++i)
        #pragma unroll
        for (int j = 0; j < 4; ++j)
            acc[i][j] = (floatx4){0.f, 0.f, 0.f, 0.f};

    #pragma unroll
    for (int kk = 0; kk < 256; kk += 32) {
        short8 af[4], bfr[4];
        #pragma unroll
        for (int mt = 0; mt < 4; ++mt) af[mt]  = *(const short8*)(ap[mt] + kk);
        #pragma unroll
        for (int nt = 0; nt < 4; ++nt) bfr[nt] = *(const short8*)(bp[nt] + kk);
        #pragma unroll
        for (int mt = 0; mt < 4; ++mt)
            #pragma unroll
            for (int nt = 0; nt < 4; ++nt)
                acc[mt][nt] = __builtin_amdgcn_mfma_f32_16x16x32_bf16(
                    af[mt], bfr[nt], acc[mt][nt], 0, 0, 0);
    }

    // epilogue: D row = wm+mt*16+quad*4+j, col = wn+nt*16+l16 (m89 mapping)
    #pragma unroll
    for (int mt = 0; mt < 4; ++mt) {
        #pragma unroll
        for (int j = 0; j < 4; ++j) {
            const int row = bm0 + wm + mt * 16 + quad * 4 + j;
            if (row >= M) continue;
            #pragma unroll
            for (int nt = 0; nt < 4; ++nt) {
                const int col = bn0 + wn + nt * 16 + l16;
                const float val = acc[mt][nt][j] + bias[col];
                if (C_BF16) ((ushort_t*)Cv)[(size_t)row * Nc + col] = f2bf(val);
                else        ((float*)Cv)[(size_t)row * Nc + col]    = val;
            }
        }
    }
}

// Fused projection GEMMs: y<2 -> vproj = v@W_in (bf16 out, Nc=256);
// y in 2..4 -> offlog = q@[W_off|W_attn] (fp32 out, Nc=384).
__global__ __launch_bounds__(256) void gemm_proj_kernel(
    const ushort_t* __restrict__ vbf, const ushort_t* __restrict__ qbf,
    const ushort_t* __restrict__ Tin, const ushort_t* __restrict__ Tcomb,
    const float* __restrict__ b_in, const float* __restrict__ bcomb,
    ushort_t* __restrict__ vproj, float* __restrict__ offlog)
{
    const int bm0 = blockIdx.x * 128;
    const int y = blockIdx.y;
    if (y < 2)
        gemm_direct<true>(vbf, Tin, b_in, vproj, M_TOT, 256, bm0, y * 128);
    else
        gemm_direct<false>(qbf, Tcomb, bcomb, offlog, M_TOT, 384, bm0, (y - 2) * 128);
}

__global__ __launch_bounds__(256) void gemm_out_kernel(
    const ushort_t* __restrict__ mid, const ushort_t* __restrict__ Tout,
    const float* __restrict__ b_out, float* __restrict__ out)
{
    gemm_direct<false>(mid, Tout, b_out, out, M_TOT, 256,
                       blockIdx.x * 128, blockIdx.y * 128);
}

// =====================================================================
// Sampling kernel v6: 2 queries per 64-thread (single-wave) block.
// Phase 2: 32 lanes/query = 8 heads x 4 lanes; each lane gathers 16B
// (8 bf16 channels) per corner -> half the VMEM instructions of v5,
// 64 independent loads in flight per lane.
// =====================================================================
#define QB 2
#define SLOTS 576

__global__ __launch_bounds__(64) void msda_sample_kernel(
    const ushort_t* __restrict__ vproj, const float* __restrict__ offlog,
    const float* __restrict__ p, ushort_t* __restrict__ mid)
{
    __shared__ float s_logit[QB][128];
    __shared__ float s_off[QB][256];
    __shared__ float s_p[QB][8];
    __shared__ float s_mx[QB][HEADS];
    __shared__ float s_inv[QB][HEADS];
    __shared__ float s_w[QB][SLOTS];
    __shared__ int   s_idx[QB][SLOTS];

    const int tid = threadIdx.x;          // 0..63
    const int bq0 = blockIdx.x * QB;

    #pragma unroll
    for (int i = tid; i < QB * 256; i += 64) {
        int sub = i >> 8, j = i & 255;
        s_off[sub][j] = offlog[(size_t)(bq0 + sub) * 384 + j];
    }
    #pragma unroll
    for (int i = tid; i < QB * 128; i += 64) {
        int sub = i >> 7, j = i & 127;
        s_logit[sub][j] = offlog[(size_t)(bq0 + sub) * 384 + 256 + j];
    }
    if (tid < QB * 8) {
        int sub = tid >> 3, j = tid & 7;
        s_p[sub][j] = p[(size_t)(bq0 + sub) * 8 + j];
    }
    __syncthreads();

    if (tid < QB * HEADS) {
        int sub = tid >> 3, h = tid & 7;
        float mx = -1e30f;
        #pragma unroll
        for (int i = 0; i < 16; ++i) mx = fmaxf(mx, s_logit[sub][h * 16 + i]);
        float ssum = 0.0f;
        #pragma unroll
        for (int i = 0; i < 16; ++i) ssum += __expf(s_logit[sub][h * 16 + i] - mx);
        s_mx[sub][h] = mx;
        s_inv[sub][h] = 1.0f / ssum;
    }
    __syncthreads();

    // ---- phase 1: 256 tasks (sub, h, l, pt) over 64 threads ----
    #pragma unroll
    for (int tt = tid; tt < QB * 128; tt += 64) {
        const int sub = tt >> 7;
        const int j   = tt & 127;          // h*16 + l*4 + pt
        const int h   = j >> 4;
        const int l   = (j >> 2) & 3;
        const int nq  = bq0 + sub;
        const int nb  = (nq >= QN) ? 1 : 0;

        const int Hl = c_Hl[l], Wl = c_Wl[l], st = c_start[l];
        const float fW = (float)Wl, fH = (float)Hl;

        const float w = __expf(s_logit[sub][j] - s_mx[sub][h]) * s_inv[sub][h];

        const int oi = j * 2;
        const float ox = s_off[sub][oi];
        const float oy = s_off[sub][oi + 1];
        const float px = s_p[sub][l * 2 + 0];
        const float py = s_p[sub][l * 2 + 1];

        const float lx = px + ox / fW;
        const float ly = py + oy / fH;
        const float x = lx * fW - 0.5f;
        const float y = ly * fH - 0.5f;

        const float x0f = floorf(x), y0f = floorf(y);
        const int x0 = (int)x0f, y0 = (int)y0f;
        const float dx = x - x0f, dy = y - y0f;

        const int base = nb * (HW_TOT * DIMS) + h * CH;
        const int slot = (j & 15) * 36 + h * 4;

        const bool vx0 = (x0 >= 0) & (x0 < Wl);
        const bool vx1 = (x0 + 1 >= 0) & (x0 + 1 < Wl);
        const bool vy0 = (y0 >= 0) & (y0 < Hl);
        const bool vy1 = (y0 + 1 >= 0) & (y0 + 1 < Hl);

        s_w[sub][slot + 0] = (vx0 & vy0) ? w * (1.0f - dx) * (1.0f - dy) : 0.0f;
        s_w[sub][slot + 1] = (vx1 & vy0) ? w * dx * (1.0f - dy) : 0.0f;
        s_w[sub][slot + 2] = (vx0 & vy1) ? w * (1.0f - dx) * dy : 0.0f;
        s_w[sub][slot + 3] = (vx1 & vy1) ? w * dx * dy : 0.0f;
        s_idx[sub][slot + 0] = (vx0 & vy0) ? base + (st + y0 * Wl + x0) * DIMS : 0;
        s_idx[sub][slot + 1] = (vx1 & vy0) ? base + (st + y0 * Wl + x0 + 1) * DIMS : 0;
        s_idx[sub][slot + 2] = (vx0 & vy1) ? base + (st + (y0 + 1) * Wl + x0) * DIMS : 0;
        s_idx[sub][slot + 3] = (vx1 & vy1) ? base + (st + (y0 + 1) * Wl + x0 + 1) * DIMS : 0;
    }
    __syncthreads();

    // ---- phase 2: 32 lanes/query, 16B bf16 gathers, fp32 accumulate ----
    const int sub    = tid >> 5;          // 0..1
    const int lane32 = tid & 31;
    const int h      = lane32 >> 2;       // 0..7
    const int c16    = lane32 & 3;        // 0..3 -> 8 channels each
    const int nq     = bq0 + sub;

    float a0=0.f,a1=0.f,a2=0.f,a3=0.f,a4=0.f,a5=0.f,a6=0.f,a7=0.f;
    const ushort_t* __restrict__ vb = vproj + c16 * 8;

    #pragma unroll
    for (int t = 0; t < 16; ++t) {
        const int slot = t * 36 + h * 4;
        const int4   I = *(const int4*)&s_idx[sub][slot];
        const float4 W = *(const float4*)&s_w[sub][slot];

        const uint4 g0 = *(const uint4*)(vb + I.x);
        const uint4 g1 = *(const uint4*)(vb + I.y);
        const uint4 g2 = *(const uint4*)(vb + I.z);
        const uint4 g3 = *(const uint4*)(vb + I.w);

        a0 = fmaf(W.x, __uint_as_float(g0.x << 16), a0);
        a1 = fmaf(W.x, __uint_as_float(g0.x & 0xffff0000u), a1);
        a2 = fmaf(W.x, __uint_as_float(g0.y << 16), a2);
        a3 = fmaf(W.x, __uint_as_float(g0.y & 0xffff0000u), a3);
        a4 = fmaf(W.x, __uint_as_float(g0.z << 16), a4);
        a5 = fmaf(W.x, __uint_as_float(g0.z & 0xffff0000u), a5);
        a6 = fmaf(W.x, __uint_as_float(g0.w << 16), a6);
        a7 = fmaf(W.x, __uint_as_float(g0.w & 0xffff0000u), a7);

        a0 = fmaf(W.y, __uint_as_float(g1.x << 16), a0);
        a1 = fmaf(W.y, __uint_as_float(g1.x & 0xffff0000u), a1);
        a2 = fmaf(W.y, __uint_as_float(g1.y << 16), a2);
        a3 = fmaf(W.y, __uint_as_float(g1.y & 0xffff0000u), a3);
        a4 = fmaf(W.y, __uint_as_float(g1.z << 16), a4);
        a5 = fmaf(W.y, __uint_as_float(g1.z & 0xffff0000u), a5);
        a6 = fmaf(W.y, __uint_as_float(g1.w << 16), a6);
        a7 = fmaf(W.y, __uint_as_float(g1.w & 0xffff0000u), a7);

        a0 = fmaf(W.z, __uint_as_float(g2.x << 16), a0);
        a1 = fmaf(W.z, __uint_as_float(g2.x & 0xffff0000u), a1);
        a2 = fmaf(W.z, __uint_as_float(g2.y << 16), a2);
        a3 = fmaf(W.z, __uint_as_float(g2.y & 0xffff0000u), a3);
        a4 = fmaf(W.z, __uint_as_float(g2.z << 16), a4);
        a5 = fmaf(W.z, __uint_as_float(g2.z & 0xffff0000u), a5);
        a6 = fmaf(W.z, __uint_as_float(g2.w << 16), a6);
        a7 = fmaf(W.z, __uint_as_float(g2.w & 0xffff0000u), a7);

        a0 = fmaf(W.w, __uint_as_float(g3.x << 16), a0);
        a1 = fmaf(W.w, __uint_as_float(g3.x & 0xffff0000u), a1);
        a2 = fmaf(W.w, __uint_as_float(g3.y << 16), a2);
        a3 = fmaf(W.w, __uint_as_float(g3.y & 0xffff0000u), a3);
        a4 = fmaf(W.w, __uint_as_float(g3.z << 16), a4);
        a5 = fmaf(W.w, __uint_as_float(g3.z & 0xffff0000u), a5);
        a6 = fmaf(W.w, __uint_as_float(g3.w << 16), a6);
        a7 = fmaf(W.w, __uint_as_float(g3.w & 0xffff0000u), a7);
    }

    ushort_t mv[8] = {f2bf(a0), f2bf(a1), f2bf(a2), f2bf(a3),
                      f2bf(a4), f2bf(a5), f2bf(a6), f2bf(a7)};
    *(int4*)&mid[(size_t)nq * DIMS + h * CH + c16 * 8] = *(int4*)mv;
}

// =====================================================================
extern "C" void kernel_launch(void* const* d_in, const int* in_sizes, int n_in,
                              void* d_out, int out_size, void* d_ws, size_t ws_size,
                              hipStream_t stream)
{
    const float* q      = (const float*)d_in[0];
    const float* p      = (const float*)d_in[1];
    const float* v      = (const float*)d_in[2];
    const float* W_off  = (const float*)d_in[3];
    const float* b_off  = (const float*)d_in[4];
    const float* W_attn = (const float*)d_in[5];
    const float* b_attn = (const float*)d_in[6];
    const float* W_in   = (const float*)d_in[7];
    const float* b_in   = (const float*)d_in[8];
    const float* W_out  = (const float*)d_in[9];
    const float* b_out  = (const float*)d_in[10];
    float* out = (float*)d_out;

    const int M = M_TOT;                            // 24480

    // workspace layout (mid aliases vbf -- vbf dead after proj GEMM)
    ushort_t* vproj  = (ushort_t*)d_ws;                          // M*256 bf16
    float*    offlog = (float*)(vproj + (size_t)M * 256);        // M*384 f32
    ushort_t* vbf    = (ushort_t*)(offlog + (size_t)M * 384);    // M*256 bf16
    ushort_t* mid    = vbf;                                      // alias
    ushort_t* qbf    = vbf + (size_t)M * 256;                    // M*256 bf16
    ushort_t* Tin    = qbf + (size_t)M * 256;
    ushort_t* Tcomb  = Tin + 256 * 256;
    ushort_t* Tout   = Tcomb + 384 * 256;
    float*    bcomb  = (float*)(Tout + 256 * 256);

    // 0a) v,q -> bf16
    convert_qv_kernel<<<dim3(6120), 256, 0, stream>>>(v, q, vbf, qbf);
    // 0b) weights -> transposed bf16 (+ fused off/attn weight & bias)
    prep_weights_kernel<<<dim3(384, 1, 3), 256, 0, stream>>>(
        W_in, W_off, W_attn, W_out, b_off, b_attn, Tin, Tcomb, Tout, bcomb);

    // 1+2+3) fused projection GEMMs (direct-load, no LDS/barriers)
    gemm_proj_kernel<<<dim3(192, 5), 256, 0, stream>>>(
        vbf, qbf, Tin, Tcomb, b_in, bcomb, vproj, offlog);
    // 4) softmax + bilinear sampling -> bf16 mid
    msda_sample_kernel<<<dim3(M / QB), 64, 0, stream>>>(vproj, offlog, p, mid);
    // 5) out = mid @ W_out + b_out
    gemm_out_kernel<<<dim3(192, 2), 256, 0, stream>>>(mid, Tout, b_out, out);
}

// Round 7
// 230.230 us; speedup vs baseline: 1.4267x; 1.4267x over previous
//
#include <hip/hip_runtime.h>
#include <hip/hip_bf16.h>
#include <math.h>

// ---- problem constants (structural, from the reference) ----
#define NB      2
#define QN      12240
#define HW_TOT  12240
#define DIMS    256
#define HEADS   8
#define CH      32
#define LEVELS  4
#define POINTS  4
#define M_TOT   (NB * QN)        // 24480

typedef unsigned short ushort_t;
typedef __attribute__((ext_vector_type(8))) short short8;
typedef __attribute__((ext_vector_type(4))) float floatx4;

__device__ __constant__ int c_Hl[4]    = {96, 48, 24, 12};
__device__ __constant__ int c_Wl[4]    = {96, 48, 24, 12};
__device__ __constant__ int c_start[4] = {0, 9216, 11520, 12096};

__device__ __forceinline__ ushort_t f2bf(float f) {
    __hip_bfloat16 h = __float2bfloat16(f);
    return *reinterpret_cast<ushort_t*>(&h);
}

// =====================================================================
// Elementwise fp32 -> bf16 for v and q (one pass, 8 elems/thread).
// =====================================================================
__global__ __launch_bounds__(256) void convert_qv_kernel(
    const float* __restrict__ v, const float* __restrict__ q,
    ushort_t* __restrict__ vbf, ushort_t* __restrict__ qbf)
{
    const size_t i = ((size_t)blockIdx.x * 256 + threadIdx.x) * 8;
    const size_t half = (size_t)M_TOT * DIMS;
    const float* src; ushort_t* dst; size_t off;
    if (i < half) { src = v; dst = vbf; off = i; }
    else          { src = q; dst = qbf; off = i - half; }
    const float4 a = *(const float4*)&src[off];
    const float4 b = *(const float4*)&src[off + 4];
    ushort_t t[8] = {f2bf(a.x), f2bf(a.y), f2bf(a.z), f2bf(a.w),
                     f2bf(b.x), f2bf(b.y), f2bf(b.z), f2bf(b.w)};
    *(int4*)&dst[off] = *(int4*)t;
}

// =====================================================================
// Weights -> transposed bf16 (WT[n][k]); z=1 also builds the fused
// off+attn weight [384][256] and its combined bias.
// =====================================================================
__global__ __launch_bounds__(256) void prep_weights_kernel(
    const float* __restrict__ W_in, const float* __restrict__ W_off,
    const float* __restrict__ W_attn, const float* __restrict__ W_out,
    const float* __restrict__ b_off, const float* __restrict__ b_attn,
    ushort_t* __restrict__ Tin, ushort_t* __restrict__ Tcomb,
    ushort_t* __restrict__ Tout, float* __restrict__ bcomb)
{
    const int z  = blockIdx.z;
    const int gi = blockIdx.x * 256 + threadIdx.x;
    if (z == 1 && gi < 384)
        bcomb[gi] = (gi < 256) ? b_off[gi] : b_attn[gi - 256];
    const int Nw = (z == 1) ? 384 : 256;
    if (gi >= Nw * 256) return;
    const int k = gi & 255;       // coalesced write along k
    const int n = gi >> 8;
    float val; ushort_t* T;
    if (z == 0)      { val = W_in[k * 256 + n];  T = Tin;  }
    else if (z == 1) { val = (n < 256) ? W_off[k * 256 + n]
                                       : W_attn[k * 128 + (n - 256)]; T = Tcomb; }
    else             { val = W_out[k * 256 + n]; T = Tout; }
    T[n * 256 + k] = f2bf(val);
}

// =====================================================================
// B-resident bf16 MFMA GEMM for K=256, tall M.
// Block: stage B-tile (128 cols x 256 K, bf16) into LDS ONCE (padded
// rows: 264 elems = 528 B, lane n-stride 132 words -> 2-way bank alias
// max = free per m136), single barrier, then stream 2 M-chunks of 128
// rows.  Per k-step/wave: 4 contiguous global dwordx4 A-frag loads +
// 4 ds_read_b128 B-frags + 16 MFMA, NO barriers in the hot loop ->
// compiler pipelines with fine-grained vmcnt across the whole chunk.
// M-tail: load rows clamped, stores guarded.
// =====================================================================
#define BPAD 264

template<bool C_BF16>
__device__ __forceinline__ void gemm_bres(
    const ushort_t* __restrict__ A, const ushort_t* __restrict__ BT,
    const float* __restrict__ bias, void* __restrict__ Cv,
    int M, int Nc, int bn0, int bm_base, ushort_t* Bs)
{
    const int tid  = threadIdx.x;
    const int wave = tid >> 6;
    const int lane = tid & 63;
    const int quad = lane >> 4;
    const int l16  = lane & 15;
    const int wm   = (wave >> 1) * 64;
    const int wn   = (wave & 1) * 64;

    // ---- stage B once: 128 rows x 256 k, 16 int4-chunks per thread ----
    #pragma unroll
    for (int i = tid; i < 4096; i += 256) {
        const int n  = i >> 5;            // 32 chunks of 8 bf16 per row
        const int kc = (i & 31) * 8;
        *(int4*)&Bs[n * BPAD + kc] = *(const int4*)&BT[(size_t)(bn0 + n) * 256 + kc];
    }
    __syncthreads();

    #pragma unroll
    for (int mc = 0; mc < 2; ++mc) {
        const int bm0 = bm_base + mc * 128;

        const ushort_t* ap[4];
        #pragma unroll
        for (int mt = 0; mt < 4; ++mt) {
            int r = bm0 + wm + mt * 16 + l16;
            if (r > M - 1) r = M - 1;
            ap[mt] = A + (size_t)r * 256 + quad * 8;
        }

        floatx4 acc[4][4];
        #pragma unroll
        for (int i = 0; i < 4; ++i)
            #pragma unroll
            for (int j = 0; j < 4; ++j)
                acc[i][j] = (floatx4){0.f, 0.f, 0.f, 0.f};

        #pragma unroll
        for (int kk = 0; kk < 256; kk += 32) {
            short8 af[4], bfr[4];
            #pragma unroll
            for (int mt = 0; mt < 4; ++mt)
                af[mt] = *(const short8*)(ap[mt] + kk);
            #pragma unroll
            for (int nt = 0; nt < 4; ++nt)
                bfr[nt] = *(const short8*)&Bs[(wn + nt * 16 + l16) * BPAD + kk + quad * 8];
            #pragma unroll
            for (int mt = 0; mt < 4; ++mt)
                #pragma unroll
                for (int nt = 0; nt < 4; ++nt)
                    acc[mt][nt] = __builtin_amdgcn_mfma_f32_16x16x32_bf16(
                        af[mt], bfr[nt], acc[mt][nt], 0, 0, 0);
        }

        // epilogue: D row = wm+mt*16+quad*4+j, col = wn+nt*16+l16 (m89)
        #pragma unroll
        for (int mt = 0; mt < 4; ++mt) {
            #pragma unroll
            for (int j = 0; j < 4; ++j) {
                const int row = bm0 + wm + mt * 16 + quad * 4 + j;
                if (row >= M) continue;
                #pragma unroll
                for (int nt = 0; nt < 4; ++nt) {
                    const int col = bn0 + wn + nt * 16 + l16;
                    const float val = acc[mt][nt][j] + bias[col];
                    if (C_BF16) ((ushort_t*)Cv)[(size_t)row * Nc + col] = f2bf(val);
                    else        ((float*)Cv)[(size_t)row * Nc + col]    = val;
                }
            }
        }
    }
}

// Fused projection GEMMs: y<2 -> vproj = v@W_in (bf16 out, Nc=256);
// y in 2..4 -> offlog = q@[W_off|W_attn] (fp32 out, Nc=384).
__global__ __launch_bounds__(256) void gemm_proj_kernel(
    const ushort_t* __restrict__ vbf, const ushort_t* __restrict__ qbf,
    const ushort_t* __restrict__ Tin, const ushort_t* __restrict__ Tcomb,
    const float* __restrict__ b_in, const float* __restrict__ bcomb,
    ushort_t* __restrict__ vproj, float* __restrict__ offlog)
{
    __shared__ ushort_t Bs[128 * BPAD];
    const int bm_base = blockIdx.x * 256;
    const int y = blockIdx.y;
    if (y < 2)
        gemm_bres<true>(vbf, Tin, b_in, vproj, M_TOT, 256, y * 128, bm_base, Bs);
    else
        gemm_bres<false>(qbf, Tcomb, bcomb, offlog, M_TOT, 384, (y - 2) * 128, bm_base, Bs);
}

__global__ __launch_bounds__(256) void gemm_out_kernel(
    const ushort_t* __restrict__ mid, const ushort_t* __restrict__ Tout,
    const float* __restrict__ b_out, float* __restrict__ out)
{
    __shared__ ushort_t Bs[128 * BPAD];
    gemm_bres<false>(mid, Tout, b_out, out, M_TOT, 256,
                     blockIdx.y * 128, blockIdx.x * 256, Bs);
}

// =====================================================================
// Sampling kernel v5 (reverted from v6 -- v6's VGPR=232 killed
// occupancy): 2 queries per 128-thread block, 8B bf16 gathers.
// =====================================================================
#define QB 2
#define SLOTS 576

__global__ __launch_bounds__(128) void msda_sample_kernel(
    const ushort_t* __restrict__ vproj, const float* __restrict__ offlog,
    const float* __restrict__ p, ushort_t* __restrict__ mid)
{
    __shared__ float s_logit[QB][128];
    __shared__ float s_off[QB][256];
    __shared__ float s_p[QB][8];
    __shared__ float s_mx[QB][HEADS];
    __shared__ float s_inv[QB][HEADS];
    __shared__ float s_w[QB][SLOTS];
    __shared__ int   s_idx[QB][SLOTS];

    const int tid = threadIdx.x;          // 0..127
    const int bq0 = blockIdx.x * QB;

    #pragma unroll
    for (int i = tid; i < QB * 256; i += 128) {
        int sub = i >> 8, j = i & 255;
        s_off[sub][j] = offlog[(size_t)(bq0 + sub) * 384 + j];
    }
    #pragma unroll
    for (int i = tid; i < QB * 128; i += 128) {
        int sub = i >> 7, j = i & 127;
        s_logit[sub][j] = offlog[(size_t)(bq0 + sub) * 384 + 256 + j];
    }
    if (tid < QB * 8) {
        int sub = tid >> 3, j = tid & 7;
        s_p[sub][j] = p[(size_t)(bq0 + sub) * 8 + j];
    }
    __syncthreads();

    if (tid < QB * HEADS) {
        int sub = tid >> 3, h = tid & 7;
        float mx = -1e30f;
        #pragma unroll
        for (int i = 0; i < 16; ++i) mx = fmaxf(mx, s_logit[sub][h * 16 + i]);
        float ssum = 0.0f;
        #pragma unroll
        for (int i = 0; i < 16; ++i) ssum += __expf(s_logit[sub][h * 16 + i] - mx);
        s_mx[sub][h] = mx;
        s_inv[sub][h] = 1.0f / ssum;
    }
    __syncthreads();

    // ---- phase 1: 256 tasks (sub, h, l, pt) over 128 threads ----
    #pragma unroll
    for (int tt = tid; tt < QB * 128; tt += 128) {
        const int sub = tt >> 7;
        const int j   = tt & 127;          // h*16 + l*4 + pt
        const int h   = j >> 4;
        const int l   = (j >> 2) & 3;
        const int nq  = bq0 + sub;
        const int nb  = (nq >= QN) ? 1 : 0;

        const int Hl = c_Hl[l], Wl = c_Wl[l], st = c_start[l];
        const float fW = (float)Wl, fH = (float)Hl;

        const float w = __expf(s_logit[sub][j] - s_mx[sub][h]) * s_inv[sub][h];

        const int oi = j * 2;
        const float ox = s_off[sub][oi];
        const float oy = s_off[sub][oi + 1];
        const float px = s_p[sub][l * 2 + 0];
        const float py = s_p[sub][l * 2 + 1];

        const float lx = px + ox / fW;
        const float ly = py + oy / fH;
        const float x = lx * fW - 0.5f;
        const float y = ly * fH - 0.5f;

        const float x0f = floorf(x), y0f = floorf(y);
        const int x0 = (int)x0f, y0 = (int)y0f;
        const float dx = x - x0f, dy = y - y0f;

        const int base = nb * (HW_TOT * DIMS) + h * CH;
        const int slot = (j & 15) * 36 + h * 4;

        const bool vx0 = (x0 >= 0) & (x0 < Wl);
        const bool vx1 = (x0 + 1 >= 0) & (x0 + 1 < Wl);
        const bool vy0 = (y0 >= 0) & (y0 < Hl);
        const bool vy1 = (y0 + 1 >= 0) & (y0 + 1 < Hl);

        s_w[sub][slot + 0] = (vx0 & vy0) ? w * (1.0f - dx) * (1.0f - dy) : 0.0f;
        s_w[sub][slot + 1] = (vx1 & vy0) ? w * dx * (1.0f - dy) : 0.0f;
        s_w[sub][slot + 2] = (vx0 & vy1) ? w * (1.0f - dx) * dy : 0.0f;
        s_w[sub][slot + 3] = (vx1 & vy1) ? w * dx * dy : 0.0f;
        s_idx[sub][slot + 0] = (vx0 & vy0) ? base + (st + y0 * Wl + x0) * DIMS : 0;
        s_idx[sub][slot + 1] = (vx1 & vy0) ? base + (st + y0 * Wl + x0 + 1) * DIMS : 0;
        s_idx[sub][slot + 2] = (vx0 & vy1) ? base + (st + (y0 + 1) * Wl + x0) * DIMS : 0;
        s_idx[sub][slot + 3] = (vx1 & vy1) ? base + (st + (y0 + 1) * Wl + x0 + 1) * DIMS : 0;
    }
    __syncthreads();

    // ---- phase 2: bf16 gathers (uint2 = 4 channels), fp32 accumulate ----
    const int sub  = tid >> 6;
    const int lane = tid & 63;
    const int h    = lane >> 3;
    const int c4   = lane & 7;
    const int nq   = bq0 + sub;

    float ax = 0.0f, ay = 0.0f, az = 0.0f, aw = 0.0f;
    const ushort_t* __restrict__ vb = vproj + c4 * 4;

    #pragma unroll
    for (int t = 0; t < 16; ++t) {
        const int slot = t * 36 + h * 4;
        const int4   I = *(const int4*)&s_idx[sub][slot];
        const float4 W = *(const float4*)&s_w[sub][slot];

        const uint2 g0 = *(const uint2*)(vb + I.x);
        const uint2 g1 = *(const uint2*)(vb + I.y);
        const uint2 g2 = *(const uint2*)(vb + I.z);
        const uint2 g3 = *(const uint2*)(vb + I.w);

        ax = fmaf(W.x, __uint_as_float(g0.x << 16), ax);
        ay = fmaf(W.x, __uint_as_float(g0.x & 0xffff0000u), ay);
        az = fmaf(W.x, __uint_as_float(g0.y << 16), az);
        aw = fmaf(W.x, __uint_as_float(g0.y & 0xffff0000u), aw);

        ax = fmaf(W.y, __uint_as_float(g1.x << 16), ax);
        ay = fmaf(W.y, __uint_as_float(g1.x & 0xffff0000u), ay);
        az = fmaf(W.y, __uint_as_float(g1.y << 16), az);
        aw = fmaf(W.y, __uint_as_float(g1.y & 0xffff0000u), aw);

        ax = fmaf(W.z, __uint_as_float(g2.x << 16), ax);
        ay = fmaf(W.z, __uint_as_float(g2.x & 0xffff0000u), ay);
        az = fmaf(W.z, __uint_as_float(g2.y << 16), az);
        aw = fmaf(W.z, __uint_as_float(g2.y & 0xffff0000u), aw);

        ax = fmaf(W.w, __uint_as_float(g3.x << 16), ax);
        ay = fmaf(W.w, __uint_as_float(g3.x & 0xffff0000u), ay);
        az = fmaf(W.w, __uint_as_float(g3.y << 16), az);
        aw = fmaf(W.w, __uint_as_float(g3.y & 0xffff0000u), aw);
    }

    ushort_t mv[4] = {f2bf(ax), f2bf(ay), f2bf(az), f2bf(aw)};
    *(uint2*)&mid[(size_t)nq * DIMS + lane * 4] = *(uint2*)mv;
}

// =====================================================================
extern "C" void kernel_launch(void* const* d_in, const int* in_sizes, int n_in,
                              void* d_out, int out_size, void* d_ws, size_t ws_size,
                              hipStream_t stream)
{
    const float* q      = (const float*)d_in[0];
    const float* p      = (const float*)d_in[1];
    const float* v      = (const float*)d_in[2];
    const float* W_off  = (const float*)d_in[3];
    const float* b_off  = (const float*)d_in[4];
    const float* W_attn = (const float*)d_in[5];
    const float* b_attn = (const float*)d_in[6];
    const float* W_in   = (const float*)d_in[7];
    const float* b_in   = (const float*)d_in[8];
    const float* W_out  = (const float*)d_in[9];
    const float* b_out  = (const float*)d_in[10];
    float* out = (float*)d_out;

    const int M = M_TOT;                            // 24480

    // workspace layout (mid aliases vbf -- vbf dead after proj GEMM)
    ushort_t* vproj  = (ushort_t*)d_ws;                          // M*256 bf16
    float*    offlog = (float*)(vproj + (size_t)M * 256);        // M*384 f32
    ushort_t* vbf    = (ushort_t*)(offlog + (size_t)M * 384);    // M*256 bf16
    ushort_t* mid    = vbf;                                      // alias
    ushort_t* qbf    = vbf + (size_t)M * 256;                    // M*256 bf16
    ushort_t* Tin    = qbf + (size_t)M * 256;
    ushort_t* Tcomb  = Tin + 256 * 256;
    ushort_t* Tout   = Tcomb + 384 * 256;
    float*    bcomb  = (float*)(Tout + 256 * 256);

    // 0a) v,q -> bf16
    convert_qv_kernel<<<dim3(6120), 256, 0, stream>>>(v, q, vbf, qbf);
    // 0b) weights -> transposed bf16 (+ fused off/attn weight & bias)
    prep_weights_kernel<<<dim3(384, 1, 3), 256, 0, stream>>>(
        W_in, W_off, W_attn, W_out, b_off, b_attn, Tin, Tcomb, Tout, bcomb);

    // 1+2+3) fused projection GEMMs (B-resident LDS, barrier-free K-loop)
    gemm_proj_kernel<<<dim3(96, 5), 256, 0, stream>>>(
        vbf, qbf, Tin, Tcomb, b_in, bcomb, vproj, offlog);
    // 4) softmax + bilinear sampling -> bf16 mid
    msda_sample_kernel<<<dim3(M / QB), 128, 0, stream>>>(vproj, offlog, p, mid);
    // 5) out = mid @ W_out + b_out
    gemm_out_kernel<<<dim3(96, 2), 256, 0, stream>>>(mid, Tout, b_out, out);
}